// Round 5
// baseline (316.975 us; speedup 1.0000x reference)
//
#include <hip/hip_runtime.h>

#define N_NODES 40000
#define N_EDGES 640000
// IN_CH = HID_CH = 128, OUT_CH = 64

constexpr int BK = 16;         // k tile
constexpr int ALDS = 64 + 4;   // A-tile LDS row stride (BM=64 + pad)

// ================= CSR build =================
__global__ __launch_bounds__(256) void k_count(
    const int* __restrict__ ei, int* __restrict__ deg) {
  int e = blockIdx.x * 256 + threadIdx.x;   // grid covers exactly N_EDGES
  atomicAdd(&deg[ei[N_EDGES + e]], 1);
}

__global__ __launch_bounds__(256) void k_scanA(
    const int* __restrict__ deg, int* __restrict__ local,
    int* __restrict__ bsum) {
  const int t = threadIdx.x;
  const int base = blockIdx.x * 1024 + t * 4;
  int v0 = 0, v1 = 0, v2 = 0, v3 = 0;
  if (base < N_NODES) {
    int4 v = *reinterpret_cast<const int4*>(deg + base);
    v0 = v.x; v1 = v.y; v2 = v.z; v3 = v.w;
  }
  const int tot = v0 + v1 + v2 + v3;
  const int lane = t & 63;
  int ws = tot;
#pragma unroll
  for (int off = 1; off < 64; off <<= 1) {
    int y = __shfl_up(ws, off, 64);
    if (lane >= off) ws += y;
  }
  __shared__ int wsum[4];
  if (lane == 63) wsum[t >> 6] = ws;
  __syncthreads();
  const int w = t >> 6;
  int wbase = 0;
#pragma unroll
  for (int i = 0; i < 4; ++i) wbase += (i < w) ? wsum[i] : 0;
  const int incl = wbase + ws;
  const int excl = incl - tot;
  if (base < N_NODES) {
    int4 o;
    o.x = excl;
    o.y = excl + v0;
    o.z = excl + v0 + v1;
    o.w = excl + v0 + v1 + v2;
    *reinterpret_cast<int4*>(local + base) = o;
  }
  if (t == 255) bsum[blockIdx.x] = incl;
}

__global__ __launch_bounds__(64) void k_scanB(
    const int* __restrict__ bsum, int* __restrict__ bbase) {
  const int t = threadIdx.x;
  int v = (t < 40) ? bsum[t] : 0;
  int ws = v;
#pragma unroll
  for (int off = 1; off < 64; off <<= 1) {
    int y = __shfl_up(ws, off, 64);
    if (t >= off) ws += y;
  }
  if (t < 40) bbase[t] = ws - v;
}

__global__ __launch_bounds__(256) void k_scanC(
    const int* __restrict__ local, const int* __restrict__ bbase,
    int* __restrict__ offs, int* __restrict__ cursor) {
  int i = blockIdx.x * 256 + threadIdx.x;
  if (i < N_NODES) {
    int v = local[i] + bbase[i >> 10];
    offs[i] = v;
    cursor[i] = v;
  }
  if (i == 0) offs[N_NODES] = N_EDGES;
}

__global__ __launch_bounds__(256) void k_fill(
    const int* __restrict__ ei, int* __restrict__ cursor,
    int* __restrict__ csr_src) {
  int e = blockIdx.x * 256 + threadIdx.x;
  int dst = ei[N_EDGES + e];
  int idx = atomicAdd(&cursor[dst], 1);
  csr_src[idx] = ei[e];
}

// ================= unified GEMM: [out0 | out1(+bias)] = A @ [Wa;Wb]^T =====
// A [40000,128]; Wa,Wb [BN/2,128]; out0/out1 [40000,BN/2], bias on out1.
// BM=64 rows/block, 256 threads, reg-prefetch single-LDS-buffer pipeline.
template <int BN>
__global__ __launch_bounds__(256) void k_gemm(
    const float* __restrict__ A, const float* __restrict__ Wa,
    const float* __restrict__ Wb, const float* __restrict__ bias,
    float* __restrict__ out0, float* __restrict__ out1) {
  constexpr int HALF = BN / 2;
  constexpr int WLDSL = BN + 4;
  constexpr int M_PER = BN / 32;   // 8 (BN=256) or 4 (BN=128)
  constexpr int CG = BN / 8;       // col groups: 32 or 16
  constexpr int WL = BN / 64;      // W float4 loads per tile: 4 or 2
  constexpr int NT = 128 / BK;     // 8

  __shared__ float sA[BK * ALDS];
  __shared__ float sW[BK * WLDSL];

  const int t = threadIdx.x;
  const int n0 = blockIdx.x * 64;

  // compute-phase coordinates
  const int r_off = (t / CG) * M_PER;   // row offset in tile
  const int c_off = (t % CG) * 8;       // col offset in [0,BN)

  // A staging: 64 rows x 16 k / 256 thr = 1 float4 each
  const int lrow = t & 63;
  const int lkc = t >> 6;               // 0..3
  const float* aptr = A + (size_t)(n0 + lrow) * 128 + lkc * 4;

  // W staging: BN rows x 16 k / 256 thr = WL float4 each
  const int wrow = (BN == 256) ? t : (t & 127);
  const int wk = (BN == 256) ? 0 : ((t >> 7) * 8);
  const float* wptr = ((wrow < HALF) ? (Wa + (size_t)wrow * 128)
                                     : (Wb + (size_t)(wrow - HALF) * 128)) + wk;

  float4 pa;
  float4 pw[WL];

  auto load_tile = [&](int kk) {
    pa = *reinterpret_cast<const float4*>(aptr + kk);
#pragma unroll
    for (int q = 0; q < WL; ++q)
      pw[q] = *reinterpret_cast<const float4*>(wptr + kk + q * 4);
  };
  auto commit_tile = [&]() {
    sA[(lkc * 4 + 0) * ALDS + lrow] = pa.x;
    sA[(lkc * 4 + 1) * ALDS + lrow] = pa.y;
    sA[(lkc * 4 + 2) * ALDS + lrow] = pa.z;
    sA[(lkc * 4 + 3) * ALDS + lrow] = pa.w;
#pragma unroll
    for (int q = 0; q < WL; ++q) {
      sW[(wk + q * 4 + 0) * WLDSL + wrow] = pw[q].x;
      sW[(wk + q * 4 + 1) * WLDSL + wrow] = pw[q].y;
      sW[(wk + q * 4 + 2) * WLDSL + wrow] = pw[q].z;
      sW[(wk + q * 4 + 3) * WLDSL + wrow] = pw[q].w;
    }
  };

  float acc[M_PER][8];
#pragma unroll
  for (int i = 0; i < M_PER; ++i)
#pragma unroll
    for (int j = 0; j < 8; ++j) acc[i][j] = 0.f;

  load_tile(0);
  commit_tile();
  __syncthreads();

  for (int tile = 0; tile < NT; ++tile) {
    if (tile + 1 < NT) load_tile((tile + 1) * BK);   // prefetch next tile
#pragma unroll
    for (int k = 0; k < BK; ++k) {
      float av[M_PER], wv[8];
#pragma unroll
      for (int q = 0; q < M_PER / 4; ++q)
        *reinterpret_cast<float4*>(&av[q * 4]) =
            *reinterpret_cast<const float4*>(&sA[k * ALDS + r_off + q * 4]);
      *reinterpret_cast<float4*>(&wv[0]) =
          *reinterpret_cast<const float4*>(&sW[k * WLDSL + c_off]);
      *reinterpret_cast<float4*>(&wv[4]) =
          *reinterpret_cast<const float4*>(&sW[k * WLDSL + c_off + 4]);
#pragma unroll
      for (int i = 0; i < M_PER; ++i)
#pragma unroll
        for (int j = 0; j < 8; ++j)
          acc[i][j] = fmaf(av[i], wv[j], acc[i][j]);
    }
    if (tile + 1 < NT) {
      __syncthreads();   // all waves done reading current LDS tile
      commit_tile();     // (waits vmcnt for prefetched regs)
      __syncthreads();   // next tile visible
    }
  }

  // epilogue: first half of cols -> out0, second half -> out1 + bias
  const bool second = (c_off >= HALF);
  const int cc = second ? (c_off - HALF) : c_off;
  float bv[8];
  if (second) {
    *reinterpret_cast<float4*>(&bv[0]) =
        *reinterpret_cast<const float4*>(bias + cc);
    *reinterpret_cast<float4*>(&bv[4]) =
        *reinterpret_cast<const float4*>(bias + cc + 4);
  } else {
#pragma unroll
    for (int j = 0; j < 8; ++j) bv[j] = 0.f;
  }
  float* dst = second ? out1 : out0;
#pragma unroll
  for (int i = 0; i < M_PER; ++i) {
    const size_t row = (size_t)(n0 + r_off + i) * HALF + cc;
    float4 o0, o1;
    o0.x = acc[i][0] + bv[0];
    o0.y = acc[i][1] + bv[1];
    o0.z = acc[i][2] + bv[2];
    o0.w = acc[i][3] + bv[3];
    o1.x = acc[i][4] + bv[4];
    o1.y = acc[i][5] + bv[5];
    o1.z = acc[i][6] + bv[6];
    o1.w = acc[i][7] + bv[7];
    *reinterpret_cast<float4*>(dst + row) = o0;
    *reinterpret_cast<float4*>(dst + row + 4) = o1;
  }
}

// ============ layer-1 gather: h[n] = relu(xo[n] + sum_{j->n} xr[j]) =======
// in-place: h aliases xo (each thread reads its own element then overwrites)
__global__ __launch_bounds__(256) void k_gather_relu(
    const float* __restrict__ xr, float* __restrict__ h,
    const int* __restrict__ csr_src, const int* __restrict__ offs) {
  int n = blockIdx.x * 4 + (threadIdx.x >> 6);
  n = __builtin_amdgcn_readfirstlane(n);
  const int lane = threadIdx.x & 63;
  const int s = offs[n], e = offs[n + 1];
  float2 a0 = make_float2(0.f, 0.f), a1 = a0, a2 = a0, a3 = a0;
  int i = s;
  for (; i + 3 < e; i += 4) {
    int s0 = csr_src[i], s1 = csr_src[i + 1];
    int s2 = csr_src[i + 2], s3 = csr_src[i + 3];
    float2 v0 = *reinterpret_cast<const float2*>(xr + (size_t)s0 * 128 + lane * 2);
    float2 v1 = *reinterpret_cast<const float2*>(xr + (size_t)s1 * 128 + lane * 2);
    float2 v2 = *reinterpret_cast<const float2*>(xr + (size_t)s2 * 128 + lane * 2);
    float2 v3 = *reinterpret_cast<const float2*>(xr + (size_t)s3 * 128 + lane * 2);
    a0.x += v0.x; a0.y += v0.y;
    a1.x += v1.x; a1.y += v1.y;
    a2.x += v2.x; a2.y += v2.y;
    a3.x += v3.x; a3.y += v3.y;
  }
  for (; i < e; ++i) {
    int s0 = csr_src[i];
    float2 v0 = *reinterpret_cast<const float2*>(xr + (size_t)s0 * 128 + lane * 2);
    a0.x += v0.x; a0.y += v0.y;
  }
  float* hp = h + (size_t)n * 128 + lane * 2;
  float2 base = *reinterpret_cast<const float2*>(hp);
  float2 r;
  r.x = fmaxf(base.x + a0.x + a1.x + a2.x + a3.x, 0.f);
  r.y = fmaxf(base.y + a0.y + a1.y + a2.y + a3.y, 0.f);
  *reinterpret_cast<float2*>(hp) = r;
}

// ============ layer-2 gather: out[n] += sum_{j->n} t2[j] (64 ch) ==========
__global__ __launch_bounds__(256) void k_gather64(
    const float* __restrict__ t2, const int* __restrict__ csr_src,
    const int* __restrict__ offs, float* __restrict__ out) {
  int n = blockIdx.x * 4 + (threadIdx.x >> 6);
  n = __builtin_amdgcn_readfirstlane(n);
  const int lane = threadIdx.x & 63;
  const int s = offs[n], e = offs[n + 1];
  float a0 = 0.f, a1 = 0.f, a2 = 0.f, a3 = 0.f;
  int i = s;
  for (; i + 3 < e; i += 4) {
    int s0 = csr_src[i], s1 = csr_src[i + 1];
    int s2 = csr_src[i + 2], s3 = csr_src[i + 3];
    a0 += t2[(size_t)s0 * 64 + lane];
    a1 += t2[(size_t)s1 * 64 + lane];
    a2 += t2[(size_t)s2 * 64 + lane];
    a3 += t2[(size_t)s3 * 64 + lane];
  }
  for (; i < e; ++i) a0 += t2[(size_t)csr_src[i] * 64 + lane];
  out[(size_t)n * 64 + lane] += (a0 + a1) + (a2 + a3);
}

extern "C" void kernel_launch(void* const* d_in, const int* in_sizes, int n_in,
                              void* d_out, int out_size, void* d_ws, size_t ws_size,
                              hipStream_t stream) {
  const float* x = (const float*)d_in[0];
  const int* ei = (const int*)d_in[1];
  const float* W1rel = (const float*)d_in[2];
  const float* W1root = (const float*)d_in[3];
  const float* b1 = (const float*)d_in[4];
  const float* W2rel = (const float*)d_in[5];
  const float* W2root = (const float*)d_in[6];
  const float* b2 = (const float*)d_in[7];
  float* out = (float*)d_out;

  // workspace layout (same footprint as R4: ~54 MB)
  float* xr = (float*)d_ws;                           // 40000*128 f
  float* xo = xr + (size_t)N_NODES * 128;             // 40000*128 f (becomes h)
  float* t2 = xo + (size_t)N_NODES * 128;             // 40000*64  f
  int* deg = (int*)(t2 + (size_t)N_NODES * 64);       // 40000 int
  int* offs = deg + N_NODES;                          // 40001 int
  int* cursor = offs + (N_NODES + 1);                 // 40000 int
  int* csr_src = cursor + N_NODES;                    // 640000 int
  int* bsum = csr_src + N_EDGES;                      // 40 int
  int* bbase = bsum + 64;                             // 40 int
  int* local = (int*)xr;                              // aliases xr (dead)

  // ---- CSR build ----
  hipMemsetAsync(deg, 0, (size_t)N_NODES * sizeof(int), stream);
  k_count<<<N_EDGES / 256, 256, 0, stream>>>(ei, deg);
  k_scanA<<<(N_NODES + 1023) / 1024, 256, 0, stream>>>(deg, local, bsum);
  k_scanB<<<1, 64, 0, stream>>>(bsum, bbase);
  k_scanC<<<(N_NODES + 255) / 256, 256, 0, stream>>>(local, bbase, offs, cursor);
  k_fill<<<N_EDGES / 256, 256, 0, stream>>>(ei, cursor, csr_src);

  // ---- layer 1 (transform-first): xr = x@W1rel.T ; xo = x@W1root.T + b1
  k_gemm<256><<<N_NODES / 64, 256, 0, stream>>>(x, W1rel, W1root, b1, xr, xo);
  // h = relu(xo + S*xr), in-place over xo
  k_gather_relu<<<N_NODES / 4, 256, 0, stream>>>(xr, xo, csr_src, offs);

  // ---- layer 2 (transform-first): t2 = h@W2rel.T ; out = h@W2root.T + b2
  k_gemm<128><<<N_NODES / 64, 256, 0, stream>>>(xo, W2rel, W2root, b2, t2, out);
  k_gather64<<<N_NODES / 4, 256, 0, stream>>>(t2, csr_src, offs, out);
}

// Round 6
// 279.455 us; speedup vs baseline: 1.1343x; 1.1343x over previous
//
#include <hip/hip_runtime.h>

#define N_NODES 40000
#define N_EDGES 640000
// IN_CH = HID_CH = 128, OUT_CH = 64

constexpr int BK = 16;         // k tile
constexpr int BM = 32;         // node rows per block (grid = 1250)
constexpr int ALDS = BM + 4;   // A-tile LDS row stride

// ================= CSR build =================
__global__ __launch_bounds__(256) void k_count(
    const int* __restrict__ ei, int* __restrict__ deg) {
  int e = blockIdx.x * 256 + threadIdx.x;   // grid covers exactly N_EDGES
  atomicAdd(&deg[ei[N_EDGES + e]], 1);
}

__global__ __launch_bounds__(256) void k_scanA(
    const int* __restrict__ deg, int* __restrict__ local,
    int* __restrict__ bsum) {
  const int t = threadIdx.x;
  const int base = blockIdx.x * 1024 + t * 4;
  int v0 = 0, v1 = 0, v2 = 0, v3 = 0;
  if (base < N_NODES) {
    int4 v = *reinterpret_cast<const int4*>(deg + base);
    v0 = v.x; v1 = v.y; v2 = v.z; v3 = v.w;
  }
  const int tot = v0 + v1 + v2 + v3;
  const int lane = t & 63;
  int ws = tot;
#pragma unroll
  for (int off = 1; off < 64; off <<= 1) {
    int y = __shfl_up(ws, off, 64);
    if (lane >= off) ws += y;
  }
  __shared__ int wsum[4];
  if (lane == 63) wsum[t >> 6] = ws;
  __syncthreads();
  const int w = t >> 6;
  int wbase = 0;
#pragma unroll
  for (int i = 0; i < 4; ++i) wbase += (i < w) ? wsum[i] : 0;
  const int incl = wbase + ws;
  const int excl = incl - tot;
  if (base < N_NODES) {
    int4 o;
    o.x = excl;
    o.y = excl + v0;
    o.z = excl + v0 + v1;
    o.w = excl + v0 + v1 + v2;
    *reinterpret_cast<int4*>(local + base) = o;
  }
  if (t == 255) bsum[blockIdx.x] = incl;
}

__global__ __launch_bounds__(64) void k_scanB(
    const int* __restrict__ bsum, int* __restrict__ bbase) {
  const int t = threadIdx.x;
  int v = (t < 40) ? bsum[t] : 0;
  int ws = v;
#pragma unroll
  for (int off = 1; off < 64; off <<= 1) {
    int y = __shfl_up(ws, off, 64);
    if (t >= off) ws += y;
  }
  if (t < 40) bbase[t] = ws - v;
}

__global__ __launch_bounds__(256) void k_scanC(
    const int* __restrict__ local, const int* __restrict__ bbase,
    int* __restrict__ offs, int* __restrict__ cursor) {
  int i = blockIdx.x * 256 + threadIdx.x;
  if (i < N_NODES) {
    int v = local[i] + bbase[i >> 10];
    offs[i] = v;
    cursor[i] = v;
  }
  if (i == 0) offs[N_NODES] = N_EDGES;
}

__global__ __launch_bounds__(256) void k_fill(
    const int* __restrict__ ei, int* __restrict__ cursor,
    int* __restrict__ csr_src) {
  int e = blockIdx.x * 256 + threadIdx.x;
  int dst = ei[N_EDGES + e];
  int idx = atomicAdd(&cursor[dst], 1);
  csr_src[idx] = ei[e];
}

// ====== unified GEMM: [out0 | out1(+bias)] = A @ [Wa;Wb]^T ======
// A [40000,128]; Wa,Wb [BN/2,128]; out0/out1 [40000,BN/2].
// BM=32 rows/block, 256 threads, 2-barrier staging (R4-proven pattern).
// Thread tile: 2 rows x (NG groups of 4 cols, groups 64 apart) -> conflict-free
// LDS reads: 16 distinct float4 addrs spanning 64 floats, 4x broadcast dup.
template <int BN>
__global__ __launch_bounds__(256) void k_gemm(
    const float* __restrict__ A, const float* __restrict__ Wa,
    const float* __restrict__ Wb, const float* __restrict__ bias,
    float* __restrict__ out0, float* __restrict__ out1) {
  constexpr int HALF = BN / 2;
  constexpr int WLDSL = BN + 4;
  constexpr int NG = BN / 64;      // col groups per thread: 4 or 2
  constexpr int WL = BN / 64;      // W float4 loads per thread per tile
  constexpr int NT = 128 / BK;     // 8

  __shared__ float sA[BK * ALDS];
  __shared__ float sW[BK * WLDSL];

  const int t = threadIdx.x;
  const int n0 = blockIdx.x * BM;

  // compute coordinates: 16 col-groups x 16 row-groups
  const int r2 = (t >> 4) << 1;    // row offset 0..30
  const int c4 = (t & 15) << 2;    // col offset 0..60 (plus 64*g)

  // A staging: 32 rows x 16 k = 128 float4s -> threads 0..127
  const int arow = t & 31;
  const int akc = (t >> 5) & 3;    // 0..3
  const float* aptr = A + (size_t)(n0 + arow) * 128 + akc * 4;

  // W staging: BN rows x 16 k / 256 thr = WL float4s each
  const int wrow = t & (BN - 1);
  const int wk = (t / BN) * (WL * 4);
  const float* wptr = ((wrow < HALF) ? (Wa + (size_t)wrow * 128)
                                     : (Wb + (size_t)(wrow - HALF) * 128)) + wk;

  float acc[2][NG * 4];
#pragma unroll
  for (int i = 0; i < 2; ++i)
#pragma unroll
    for (int j = 0; j < NG * 4; ++j) acc[i][j] = 0.f;

  for (int tile = 0; tile < NT; ++tile) {
    const int kk = tile * BK;
    __syncthreads();   // previous tile's reads done
    if (t < 128) {
      float4 va = *reinterpret_cast<const float4*>(aptr + kk);
      sA[(akc * 4 + 0) * ALDS + arow] = va.x;
      sA[(akc * 4 + 1) * ALDS + arow] = va.y;
      sA[(akc * 4 + 2) * ALDS + arow] = va.z;
      sA[(akc * 4 + 3) * ALDS + arow] = va.w;
    }
#pragma unroll
    for (int q = 0; q < WL; ++q) {
      float4 vw = *reinterpret_cast<const float4*>(wptr + kk + q * 4);
      sW[(wk + q * 4 + 0) * WLDSL + wrow] = vw.x;
      sW[(wk + q * 4 + 1) * WLDSL + wrow] = vw.y;
      sW[(wk + q * 4 + 2) * WLDSL + wrow] = vw.z;
      sW[(wk + q * 4 + 3) * WLDSL + wrow] = vw.w;
    }
    __syncthreads();   // tile visible
#pragma unroll
    for (int k = 0; k < BK; ++k) {
      float av0 = sA[k * ALDS + r2];
      float av1 = sA[k * ALDS + r2 + 1];
      float wv[NG * 4];
#pragma unroll
      for (int g = 0; g < NG; ++g)
        *reinterpret_cast<float4*>(&wv[g * 4]) =
            *reinterpret_cast<const float4*>(&sW[k * WLDSL + g * 64 + c4]);
#pragma unroll
      for (int j = 0; j < NG * 4; ++j) {
        acc[0][j] = fmaf(av0, wv[j], acc[0][j]);
        acc[1][j] = fmaf(av1, wv[j], acc[1][j]);
      }
    }
  }

  // epilogue: groups [0, NG/2) -> out0 ; [NG/2, NG) -> out1 (+bias)
#pragma unroll
  for (int g = 0; g < NG; ++g) {
    const bool second = (g >= NG / 2);
    const int col = (second ? (g - NG / 2) : g) * 64 + c4;
    float* dst = second ? out1 : out0;
    float4 bv = make_float4(0.f, 0.f, 0.f, 0.f);
    if (second) bv = *reinterpret_cast<const float4*>(bias + col);
#pragma unroll
    for (int i = 0; i < 2; ++i) {
      float4 o;
      o.x = acc[i][g * 4 + 0] + bv.x;
      o.y = acc[i][g * 4 + 1] + bv.y;
      o.z = acc[i][g * 4 + 2] + bv.z;
      o.w = acc[i][g * 4 + 3] + bv.w;
      *reinterpret_cast<float4*>(dst + (size_t)(n0 + r2 + i) * HALF + col) = o;
    }
  }
}

// ============ layer-1 gather: h[n] = relu(xo[n] + sum_{j->n} xr[j]) =======
__global__ __launch_bounds__(256) void k_gather_relu(
    const float* __restrict__ xr, float* __restrict__ h,
    const int* __restrict__ csr_src, const int* __restrict__ offs) {
  int n = blockIdx.x * 4 + (threadIdx.x >> 6);
  n = __builtin_amdgcn_readfirstlane(n);
  const int lane = threadIdx.x & 63;
  const int s = offs[n], e = offs[n + 1];
  float2 a0 = make_float2(0.f, 0.f), a1 = a0, a2 = a0, a3 = a0;
  int i = s;
  for (; i + 3 < e; i += 4) {
    int s0 = csr_src[i], s1 = csr_src[i + 1];
    int s2 = csr_src[i + 2], s3 = csr_src[i + 3];
    float2 v0 = *reinterpret_cast<const float2*>(xr + (size_t)s0 * 128 + lane * 2);
    float2 v1 = *reinterpret_cast<const float2*>(xr + (size_t)s1 * 128 + lane * 2);
    float2 v2 = *reinterpret_cast<const float2*>(xr + (size_t)s2 * 128 + lane * 2);
    float2 v3 = *reinterpret_cast<const float2*>(xr + (size_t)s3 * 128 + lane * 2);
    a0.x += v0.x; a0.y += v0.y;
    a1.x += v1.x; a1.y += v1.y;
    a2.x += v2.x; a2.y += v2.y;
    a3.x += v3.x; a3.y += v3.y;
  }
  for (; i < e; ++i) {
    int s0 = csr_src[i];
    float2 v0 = *reinterpret_cast<const float2*>(xr + (size_t)s0 * 128 + lane * 2);
    a0.x += v0.x; a0.y += v0.y;
  }
  float* hp = h + (size_t)n * 128 + lane * 2;
  float2 base = *reinterpret_cast<const float2*>(hp);
  float2 r;
  r.x = fmaxf(base.x + a0.x + a1.x + a2.x + a3.x, 0.f);
  r.y = fmaxf(base.y + a0.y + a1.y + a2.y + a3.y, 0.f);
  *reinterpret_cast<float2*>(hp) = r;
}

// ============ layer-2 gather: out[n] += sum_{j->n} t2[j] (64 ch) ==========
__global__ __launch_bounds__(256) void k_gather64(
    const float* __restrict__ t2, const int* __restrict__ csr_src,
    const int* __restrict__ offs, float* __restrict__ out) {
  int n = blockIdx.x * 4 + (threadIdx.x >> 6);
  n = __builtin_amdgcn_readfirstlane(n);
  const int lane = threadIdx.x & 63;
  const int s = offs[n], e = offs[n + 1];
  float a0 = 0.f, a1 = 0.f, a2 = 0.f, a3 = 0.f;
  int i = s;
  for (; i + 3 < e; i += 4) {
    int s0 = csr_src[i], s1 = csr_src[i + 1];
    int s2 = csr_src[i + 2], s3 = csr_src[i + 3];
    a0 += t2[(size_t)s0 * 64 + lane];
    a1 += t2[(size_t)s1 * 64 + lane];
    a2 += t2[(size_t)s2 * 64 + lane];
    a3 += t2[(size_t)s3 * 64 + lane];
  }
  for (; i < e; ++i) a0 += t2[(size_t)csr_src[i] * 64 + lane];
  out[(size_t)n * 64 + lane] += (a0 + a1) + (a2 + a3);
}

extern "C" void kernel_launch(void* const* d_in, const int* in_sizes, int n_in,
                              void* d_out, int out_size, void* d_ws, size_t ws_size,
                              hipStream_t stream) {
  const float* x = (const float*)d_in[0];
  const int* ei = (const int*)d_in[1];
  const float* W1rel = (const float*)d_in[2];
  const float* W1root = (const float*)d_in[3];
  const float* b1 = (const float*)d_in[4];
  const float* W2rel = (const float*)d_in[5];
  const float* W2root = (const float*)d_in[6];
  const float* b2 = (const float*)d_in[7];
  float* out = (float*)d_out;

  // workspace layout
  float* xr = (float*)d_ws;                           // 40000*128 f
  float* xo = xr + (size_t)N_NODES * 128;             // 40000*128 f (becomes h)
  float* t2 = xo + (size_t)N_NODES * 128;             // 40000*64  f
  int* deg = (int*)(t2 + (size_t)N_NODES * 64);       // 40000 int
  int* offs = deg + N_NODES;                          // 40001 int
  int* cursor = offs + (N_NODES + 1);                 // 40000 int
  int* csr_src = cursor + N_NODES;                    // 640000 int
  int* bsum = csr_src + N_EDGES;                      // 40 int
  int* bbase = bsum + 64;                             // 40 int
  int* local = (int*)xr;                              // aliases xr (dead)

  // ---- CSR build ----
  hipMemsetAsync(deg, 0, (size_t)N_NODES * sizeof(int), stream);
  k_count<<<N_EDGES / 256, 256, 0, stream>>>(ei, deg);
  k_scanA<<<(N_NODES + 1023) / 1024, 256, 0, stream>>>(deg, local, bsum);
  k_scanB<<<1, 64, 0, stream>>>(bsum, bbase);
  k_scanC<<<(N_NODES + 255) / 256, 256, 0, stream>>>(local, bbase, offs, cursor);
  k_fill<<<N_EDGES / 256, 256, 0, stream>>>(ei, cursor, csr_src);

  // ---- layer 1 (transform-first): xr = x@W1rel.T ; xo = x@W1root.T + b1
  k_gemm<256><<<N_NODES / BM, 256, 0, stream>>>(x, W1rel, W1root, b1, xr, xo);
  // h = relu(xo + S*xr), in-place over xo
  k_gather_relu<<<N_NODES / 4, 256, 0, stream>>>(xr, xo, csr_src, offs);

  // ---- layer 2 (transform-first): t2 = h@W2rel.T ; out = h@W2root.T + b2
  k_gemm<128><<<N_NODES / BM, 256, 0, stream>>>(xo, W2rel, W2root, b2, t2, out);
  k_gather64<<<N_NODES / 4, 256, 0, stream>>>(t2, csr_src, offs, out);
}

// Round 8
// 240.199 us; speedup vs baseline: 1.3196x; 1.1634x over previous
//
#include <hip/hip_runtime.h>

#define N_NODES 40000
#define N_EDGES 640000
// IN_CH = HID_CH = 128, OUT_CH = 64

typedef __attribute__((ext_vector_type(8))) short short8;
typedef __attribute__((ext_vector_type(4))) float f32x4;

__device__ __forceinline__ float b2f_hi(uint v) {           // high ushort -> f32
  uint u = v & 0xffff0000u;
  return __builtin_bit_cast(float, u);
}
__device__ __forceinline__ float b2f_lo(uint v) {           // low ushort -> f32
  uint u = v << 16;
  return __builtin_bit_cast(float, u);
}
__device__ __forceinline__ ushort f2b(float f) {            // RNE f32 -> bf16
  uint u = __builtin_bit_cast(uint, f);
  u += 0x7fffu + ((u >> 16) & 1u);
  return (ushort)(u >> 16);
}

// ================= CSR build =================
__global__ __launch_bounds__(256) void k_count(
    const int* __restrict__ ei, int* __restrict__ deg) {
  int e = blockIdx.x * 256 + threadIdx.x;   // grid covers exactly N_EDGES
  atomicAdd(&deg[ei[N_EDGES + e]], 1);
}

__global__ __launch_bounds__(256) void k_scanA(
    const int* __restrict__ deg, int* __restrict__ local,
    int* __restrict__ bsum) {
  const int t = threadIdx.x;
  const int base = blockIdx.x * 1024 + t * 4;
  int v0 = 0, v1 = 0, v2 = 0, v3 = 0;
  if (base < N_NODES) {
    int4 v = *reinterpret_cast<const int4*>(deg + base);
    v0 = v.x; v1 = v.y; v2 = v.z; v3 = v.w;
  }
  const int tot = v0 + v1 + v2 + v3;
  const int lane = t & 63;
  int ws = tot;
#pragma unroll
  for (int off = 1; off < 64; off <<= 1) {
    int y = __shfl_up(ws, off, 64);
    if (lane >= off) ws += y;
  }
  __shared__ int wsum[4];
  if (lane == 63) wsum[t >> 6] = ws;
  __syncthreads();
  const int w = t >> 6;
  int wbase = 0;
#pragma unroll
  for (int i = 0; i < 4; ++i) wbase += (i < w) ? wsum[i] : 0;
  const int incl = wbase + ws;
  const int excl = incl - tot;
  if (base < N_NODES) {
    int4 o;
    o.x = excl;
    o.y = excl + v0;
    o.z = excl + v0 + v1;
    o.w = excl + v0 + v1 + v2;
    *reinterpret_cast<int4*>(local + base) = o;
  }
  if (t == 255) bsum[blockIdx.x] = incl;
}

__global__ __launch_bounds__(64) void k_scanB(
    const int* __restrict__ bsum, int* __restrict__ bbase) {
  const int t = threadIdx.x;
  int v = (t < 40) ? bsum[t] : 0;
  int ws = v;
#pragma unroll
  for (int off = 1; off < 64; off <<= 1) {
    int y = __shfl_up(ws, off, 64);
    if (t >= off) ws += y;
  }
  if (t < 40) bbase[t] = ws - v;
}

__global__ __launch_bounds__(256) void k_scanC(
    const int* __restrict__ local, const int* __restrict__ bbase,
    int* __restrict__ offs, int* __restrict__ cursor) {
  int i = blockIdx.x * 256 + threadIdx.x;
  if (i < N_NODES) {
    int v = local[i] + bbase[i >> 10];
    offs[i] = v;
    cursor[i] = v;
  }
  if (i == 0) offs[N_NODES] = N_EDGES;
}

__global__ __launch_bounds__(256) void k_fill(
    const int* __restrict__ ei, int* __restrict__ cursor,
    int* __restrict__ csr_src) {
  int e = blockIdx.x * 256 + threadIdx.x;
  int dst = ei[N_EDGES + e];
  int idx = atomicAdd(&cursor[dst], 1);
  csr_src[idx] = ei[e];
}

// ================= fp32 -> bf16 conversions =================
// x [40000][128] -> xb bf16 ; 8 elems/thread, 2500 blocks exact
__global__ __launch_bounds__(256) void k_cvt_x(
    const float* __restrict__ x, ushort* __restrict__ xb) {
  const int i = (blockIdx.x * 256 + threadIdx.x) * 8;
  float4 v0 = *reinterpret_cast<const float4*>(x + i);
  float4 v1 = *reinterpret_cast<const float4*>(x + i + 4);
  uint4 o;
  o.x = (uint)f2b(v0.x) | ((uint)f2b(v0.y) << 16);
  o.y = (uint)f2b(v0.z) | ((uint)f2b(v0.w) << 16);
  o.z = (uint)f2b(v1.x) | ((uint)f2b(v1.y) << 16);
  o.w = (uint)f2b(v1.z) | ((uint)f2b(v1.w) << 16);
  *reinterpret_cast<uint4*>(xb + i) = o;
}

// Wb1[256][128] = [W1rel ; W1root] ; Wb2[128][128] = [W2rel ; W2root]
// flat 49152 elems, 4/thread, 48 blocks exact
__global__ __launch_bounds__(256) void k_cvt_w(
    const float* __restrict__ W1rel, const float* __restrict__ W1root,
    const float* __restrict__ W2rel, const float* __restrict__ W2root,
    ushort* __restrict__ Wb1, ushort* __restrict__ Wb2) {
  const int i = (blockIdx.x * 256 + threadIdx.x) * 4;
  const float* src;
  ushort* dst;
  if (i < 32768) {
    dst = Wb1 + i;
    src = (i < 16384) ? (W1rel + i) : (W1root + (i - 16384));
  } else {
    int j = i - 32768;
    dst = Wb2 + j;
    src = (j < 8192) ? (W2rel + j) : (W2root + (j - 8192));
  }
  float4 v = *reinterpret_cast<const float4*>(src);
  uint2 o;
  o.x = (uint)f2b(v.x) | ((uint)f2b(v.y) << 16);
  o.y = (uint)f2b(v.z) | ((uint)f2b(v.w) << 16);
  *reinterpret_cast<uint2*>(dst) = o;
}

// ================= MFMA GEMM (bf16 in, fp32 accum) =================
// [out0 | out1(+bias)] = A @ Wb^T ; A [40000][128] bf16 row-major,
// Wb [NCT*16][128] bf16 (stacked Wa;Wb). Per wave: 16 rows x all cols,
// no LDS — W rows served from L2 (hot across all 625 blocks).
// Fragment layout (m89-verified): A lane: row=l&15, k=(l>>4)*8+j;
// D lane: col=l&15, row=(l>>4)*4+i.
template <int NCT, bool F32OUT1>
__global__ __launch_bounds__(256) void k_gemm_mfma(
    const ushort* __restrict__ A, const ushort* __restrict__ Wb,
    const float* __restrict__ bias, ushort* __restrict__ out0,
    void* __restrict__ out1v) {
  constexpr int HC = NCT * 8;      // cols per output half (128 or 64)
  const int t = threadIdx.x;
  const int lane = t & 63;
  const int n0 = blockIdx.x * 64 + (t >> 6) * 16;   // wave's row base
  const int lr = lane & 15;
  const int hk = (lane >> 4) * 8;

  const ushort* arow = A + (size_t)(n0 + lr) * 128 + hk;
  const short8 a0 = *reinterpret_cast<const short8*>(arow);
  const short8 a1 = *reinterpret_cast<const short8*>(arow + 32);
  const short8 a2 = *reinterpret_cast<const short8*>(arow + 64);
  const short8 a3 = *reinterpret_cast<const short8*>(arow + 96);

  const int orow = n0 + (lane >> 4) * 4;

#pragma unroll
  for (int ct = 0; ct < NCT; ++ct) {
    const ushort* wrow = Wb + (size_t)(ct * 16 + lr) * 128 + hk;
    f32x4 acc = {0.f, 0.f, 0.f, 0.f};
    acc = __builtin_amdgcn_mfma_f32_16x16x32_bf16(
        a0, *reinterpret_cast<const short8*>(wrow), acc, 0, 0, 0);
    acc = __builtin_amdgcn_mfma_f32_16x16x32_bf16(
        a1, *reinterpret_cast<const short8*>(wrow + 32), acc, 0, 0, 0);
    acc = __builtin_amdgcn_mfma_f32_16x16x32_bf16(
        a2, *reinterpret_cast<const short8*>(wrow + 64), acc, 0, 0, 0);
    acc = __builtin_amdgcn_mfma_f32_16x16x32_bf16(
        a3, *reinterpret_cast<const short8*>(wrow + 96), acc, 0, 0, 0);

    if (ct < NCT / 2) {
      const int col = ct * 16 + lr;
#pragma unroll
      for (int i = 0; i < 4; ++i)
        out0[(size_t)(orow + i) * HC + col] = f2b(acc[i]);
    } else {
      const int col = (ct - NCT / 2) * 16 + lr;
      const float bb = bias[col];
      if (F32OUT1) {
        float* o1 = (float*)out1v;
#pragma unroll
        for (int i = 0; i < 4; ++i)
          o1[(size_t)(orow + i) * HC + col] = acc[i] + bb;
      } else {
        ushort* o1 = (ushort*)out1v;
#pragma unroll
        for (int i = 0; i < 4; ++i)
          o1[(size_t)(orow + i) * HC + col] = f2b(acc[i] + bb);
      }
    }
  }
}

// ====== layer-1 gather: h[n] = relu(xo[n] + sum_{j->n} xr[j]) (bf16) ======
// in-place over xo; one wave per node, 2 ch/lane (uint = 2 bf16)
__global__ __launch_bounds__(256) void k_gather_relu(
    const ushort* __restrict__ xr, ushort* __restrict__ h,
    const int* __restrict__ csr_src, const int* __restrict__ offs) {
  int n = blockIdx.x * 4 + (threadIdx.x >> 6);
  n = __builtin_amdgcn_readfirstlane(n);
  const int lane = threadIdx.x & 63;
  const int s = offs[n], e = offs[n + 1];
  float s00 = 0.f, s01 = 0.f, s10 = 0.f, s11 = 0.f;
  float s20 = 0.f, s21 = 0.f, s30 = 0.f, s31 = 0.f;
  int i = s;
  for (; i + 3 < e; i += 4) {
    int e0 = csr_src[i], e1 = csr_src[i + 1];
    int e2 = csr_src[i + 2], e3 = csr_src[i + 3];
    uint v0 = *reinterpret_cast<const uint*>(xr + (size_t)e0 * 128 + lane * 2);
    uint v1 = *reinterpret_cast<const uint*>(xr + (size_t)e1 * 128 + lane * 2);
    uint v2 = *reinterpret_cast<const uint*>(xr + (size_t)e2 * 128 + lane * 2);
    uint v3 = *reinterpret_cast<const uint*>(xr + (size_t)e3 * 128 + lane * 2);
    s00 += b2f_lo(v0); s01 += b2f_hi(v0);
    s10 += b2f_lo(v1); s11 += b2f_hi(v1);
    s20 += b2f_lo(v2); s21 += b2f_hi(v2);
    s30 += b2f_lo(v3); s31 += b2f_hi(v3);
  }
  for (; i < e; ++i) {
    uint v = *reinterpret_cast<const uint*>(
        xr + (size_t)csr_src[i] * 128 + lane * 2);
    s00 += b2f_lo(v); s01 += b2f_hi(v);
  }
  const float g0 = (s00 + s10) + (s20 + s30);
  const float g1 = (s01 + s11) + (s21 + s31);
  ushort* hp = h + (size_t)n * 128 + lane * 2;
  uint xov = *reinterpret_cast<const uint*>(hp);
  float r0 = fmaxf(b2f_lo(xov) + g0, 0.f);
  float r1 = fmaxf(b2f_hi(xov) + g1, 0.f);
  *reinterpret_cast<uint*>(hp) = (uint)f2b(r0) | ((uint)f2b(r1) << 16);
}

// ====== layer-2 gather: out[n] += sum_{j->n} t2[j] (bf16 -> fp32) ======
__global__ __launch_bounds__(256) void k_gather64(
    const ushort* __restrict__ t2, const int* __restrict__ csr_src,
    const int* __restrict__ offs, float* __restrict__ out) {
  int n = blockIdx.x * 4 + (threadIdx.x >> 6);
  n = __builtin_amdgcn_readfirstlane(n);
  const int lane = threadIdx.x & 63;
  const int s = offs[n], e = offs[n + 1];
  float a0 = 0.f, a1 = 0.f, a2 = 0.f, a3 = 0.f;
  int i = s;
  for (; i + 3 < e; i += 4) {
    int e0 = csr_src[i], e1 = csr_src[i + 1];
    int e2 = csr_src[i + 2], e3 = csr_src[i + 3];
    a0 += b2f_lo((uint)t2[(size_t)e0 * 64 + lane]);
    a1 += b2f_lo((uint)t2[(size_t)e1 * 64 + lane]);
    a2 += b2f_lo((uint)t2[(size_t)e2 * 64 + lane]);
    a3 += b2f_lo((uint)t2[(size_t)e3 * 64 + lane]);
  }
  for (; i < e; ++i)
    a0 += b2f_lo((uint)t2[(size_t)csr_src[i] * 64 + lane]);
  out[(size_t)n * 64 + lane] += (a0 + a1) + (a2 + a3);
}

extern "C" void kernel_launch(void* const* d_in, const int* in_sizes, int n_in,
                              void* d_out, int out_size, void* d_ws, size_t ws_size,
                              hipStream_t stream) {
  const float* x = (const float*)d_in[0];
  const int* ei = (const int*)d_in[1];
  const float* W1rel = (const float*)d_in[2];
  const float* W1root = (const float*)d_in[3];
  const float* b1 = (const float*)d_in[4];
  const float* W2rel = (const float*)d_in[5];
  const float* W2root = (const float*)d_in[6];
  const float* b2 = (const float*)d_in[7];
  float* out = (float*)d_out;

  // workspace layout (bf16 = ushort)
  ushort* xb = (ushort*)d_ws;                          // 5,120,000 us
  ushort* xr = xb + (size_t)N_NODES * 128;             // 5,120,000 us
  ushort* xo = xr + (size_t)N_NODES * 128;             // 5,120,000 us (becomes h)
  ushort* t2 = xo + (size_t)N_NODES * 128;             // 2,560,000 us
  ushort* Wb1 = t2 + (size_t)N_NODES * 64;             // 32768 us
  ushort* Wb2 = Wb1 + 32768;                           // 16384 us
  int* deg = (int*)(Wb2 + 16384);                      // 40000 int
  int* offs = deg + N_NODES;                           // 40001 int
  int* cursor = offs + (N_NODES + 1);                  // 40000 int
  int* csr_src = cursor + N_NODES;                     // 640000 int
  int* bsum = csr_src + N_EDGES;                       // 40 int
  int* bbase = bsum + 64;                              // 40 int
  int* local = (int*)xr;   // scanA scratch aliases xr (xr written later by gemm1)

  // ---- conversions (independent of CSR) ----
  k_cvt_x<<<(N_NODES * 128 / 8) / 256, 256, 0, stream>>>(x, xb);
  k_cvt_w<<<48, 256, 0, stream>>>(W1rel, W1root, W2rel, W2root, Wb1, Wb2);

  // ---- CSR build ----
  hipMemsetAsync(deg, 0, (size_t)N_NODES * sizeof(int), stream);
  k_count<<<N_EDGES / 256, 256, 0, stream>>>(ei, deg);
  k_scanA<<<(N_NODES + 1023) / 1024, 256, 0, stream>>>(deg, local, bsum);
  k_scanB<<<1, 64, 0, stream>>>(bsum, bbase);
  k_scanC<<<(N_NODES + 255) / 256, 256, 0, stream>>>(local, bbase, offs, cursor);
  k_fill<<<N_EDGES / 256, 256, 0, stream>>>(ei, cursor, csr_src);

  // ---- layer 1 (transform-first, MFMA): xr = x@W1rel.T ; xo = x@W1root.T + b1
  k_gemm_mfma<16, false><<<N_NODES / 64, 256, 0, stream>>>(
      xb, Wb1, b1, xr, (void*)xo);
  // h = relu(xo + S*xr), in-place over xo (bf16)
  k_gather_relu<<<N_NODES / 4, 256, 0, stream>>>(xr, xo, csr_src, offs);

  // ---- layer 2 (transform-first, MFMA): t2 = h@W2rel.T ; out = h@W2root.T + b2
  k_gemm_mfma<8, true><<<N_NODES / 64, 256, 0, stream>>>(
      xo, Wb2, b2, t2, (void*)out);
  k_gather64<<<N_NODES / 4, 256, 0, stream>>>(t2, csr_src, offs, out);
}